// Round 19
// baseline (1148.266 us; speedup 1.0000x reference)
//
#include <hip/hip_runtime.h>

#define NN      50000
#define NE      800000
#define INCH    8
#define CH      128
#define EA      6
#define NB      2000
#define NB_PAD  2048
#define NCLS    32
#define FUS     384
#define K1      2816   // 1408 + 1024 + 384

typedef _Float16 half8 __attribute__((ext_vector_type(8)));
typedef _Float16 h2 __attribute__((ext_vector_type(2)));
typedef float f32x4 __attribute__((ext_vector_type(4)));

// ---------- degree of dst nodes ----------
__global__ __launch_bounds__(256) void k_deg(const int* __restrict__ edge,
                                             int* __restrict__ deg) {
  int e = blockIdx.x * 256 + threadIdx.x;
  if (e < NE) atomicAdd(&deg[edge[NE + e]], 1);
}

// ---------- exclusive scan of deg -> row_ptr (single block, shfl scan) ----------
__global__ __launch_bounds__(1024) void k_scan(const int* __restrict__ deg,
                                               int* __restrict__ row_ptr) {
  __shared__ int wsum[16];
  __shared__ int s_carry;
  const int t = threadIdx.x, lane = t & 63, w = t >> 6;
  if (t == 0) s_carry = 0;
  __syncthreads();
  for (int base = 0; base < NN; base += 1024) {
    int i = base + t;
    int x = (i < NN) ? deg[i] : 0;
#pragma unroll
    for (int off = 1; off < 64; off <<= 1) {
      int y = __shfl_up(x, off, 64);
      if (lane >= off) x += y;
    }
    if (lane == 63) wsum[w] = x;
    __syncthreads();
    if (w == 0 && lane < 16) {
      int s = wsum[lane];
#pragma unroll
      for (int off = 1; off < 16; off <<= 1) {
        int y = __shfl_up(s, off, 64);
        if (lane >= off) s += y;
      }
      wsum[lane] = s;
    }
    __syncthreads();
    int incl = x + ((w == 0) ? 0 : wsum[w - 1]) + s_carry;
    if (i < NN) row_ptr[i + 1] = incl;
    __syncthreads();
    if (t == 1023) s_carry = incl;
    __syncthreads();
  }
  if (t == 0) row_ptr[0] = 0;
}

// ---------- fill CSR payload: dst-sorted src + f16 e_attr ----------
__global__ __launch_bounds__(256) void k_fill(
    const int* __restrict__ edge, const float* __restrict__ eattr,
    const int* __restrict__ row_ptr, int* __restrict__ cursor,
    int* __restrict__ ssrc, _Float16* __restrict__ sea8) {
  int e = blockIdx.x * 256 + threadIdx.x;
  if (e >= NE) return;
  int s = edge[e], d = edge[NE + e];
  int idx = row_ptr[d] + atomicAdd(&cursor[d], 1);
  ssrc[idx] = s;
  half8 v;
#pragma unroll
  for (int j = 0; j < EA; ++j) v[j] = (_Float16)eattr[(size_t)e * EA + j];
  v[6] = (_Float16)0.f; v[7] = (_Float16)0.f;
  *(half8*)(sea8 + (size_t)idx * 8) = v;
}

// ---------- segment starts from sorted bbox_idx ----------
__global__ __launch_bounds__(256) void k_segstart(const int* __restrict__ bbox,
                                                  int* __restrict__ seg) {
  int i = blockIdx.x * 256 + threadIdx.x;
  if (i >= NN) return;
  int bc = bbox[i];
  int bp = (i == 0) ? -1 : bbox[i - 1];
  for (int j = bp + 1; j <= bc; ++j) seg[j] = i;
  if (i == NN - 1)
    for (int j = bc + 1; j <= NB; ++j) seg[j] = NN;
}

// ---------- head node transform (K=8): scalar path -> interleaved f16 ----------
__global__ __launch_bounds__(256) void k_node_pq(
    const float* __restrict__ X, int ldx, int K,
    const float* __restrict__ W, const float* __restrict__ bias,
    _Float16* __restrict__ PQi, _Float16* __restrict__ Qi, int sel) {
  const int t = threadIdx.x, lane = t & 63, wv = t >> 6;
  const int nbase = blockIdx.x * 32 + wv * 8;
  const int c = lane * 2;
  const float2 bv = *(const float2*)(bias + c);
  float2 pacc[8], qacc[8];
#pragma unroll
  for (int u = 0; u < 8; ++u) { pacc[u] = bv; qacc[u] = make_float2(0.f, 0.f); }
  const int xrow = min(nbase + (lane >> 3), NN - 1);
  const int xk = lane & 7;
  for (int k0 = 0; k0 < K; k0 += 8) {
    const float xv = X[(size_t)xrow * ldx + k0 + xk];
#pragma unroll
    for (int j = 0; j < 8; ++j) {
      const float2 w1 = *(const float2*)(W + (size_t)(k0 + j) * CH + c);
      const float2 w2 = *(const float2*)(W + (size_t)(K + k0 + j) * CH + c);
      const float2 wd = {w1.x - w2.x, w1.y - w2.y};
#pragma unroll
      for (int u = 0; u < 8; ++u) {
        const float xs = __shfl(xv, u * 8 + j, 64);
        pacc[u].x += xs * wd.x; pacc[u].y += xs * wd.y;
        qacc[u].x += xs * w2.x; qacc[u].y += xs * w2.y;
      }
    }
  }
#pragma unroll
  for (int u = 0; u < 8; ++u) {
    const int node = nbase + u;
    if (node < NN) {
      const size_t o = ((size_t)node * 64 + lane) * 4 + sel * 2;
      *(h2*)(PQi + o) = (h2){(_Float16)pacc[u].x, (_Float16)pacc[u].y};
      *(h2*)(Qi + o)  = (h2){(_Float16)qacc[u].x, (_Float16)qacc[u].y};
    }
  }
}

// ---------- pack [W1-W2 | W2] (K=128 x N=256) into f16 B-fragments ----------
__global__ __launch_bounds__(64) void k_cvtWnpq(
    const float* __restrict__ WN, const float* __restrict__ WS,
    _Float16* __restrict__ whN, _Float16* __restrict__ whS) {
  const float* W = blockIdx.y ? WS : WN;
  _Float16* wh   = blockIdx.y ? whS : whN;
  const int c = blockIdx.x >> 4, tile = blockIdx.x & 15;
  const int L = threadIdx.x;
  const int n = tile * 16 + (L & 15);
  const int k0 = c * 32 + (L >> 4) * 8;
  half8 v;
#pragma unroll
  for (int j = 0; j < 8; ++j) {
    const int k = k0 + j;
    float val;
    if (n < CH) val = W[(size_t)k * CH + n] - W[(size_t)(CH + k) * CH + n];
    else        val = W[(size_t)(CH + k) * CH + (n - CH)];
    v[j] = (_Float16)val;
  }
  *(half8*)(wh + (((size_t)(c * 16 + tile)) * 64 + L) * 8) = v;
}

// ---------- residual node transform on matrix cores (both streams) ----------
__global__ __launch_bounds__(256) void k_npq_mfma(
    const float* __restrict__ Xn, const float* __restrict__ Xs, int ldx,
    const _Float16* __restrict__ whN, const _Float16* __restrict__ whS,
    const float* __restrict__ biasN, const float* __restrict__ biasS,
    _Float16* __restrict__ PQi, _Float16* __restrict__ Qi) {
  const int sel = blockIdx.y;
  const float* X = sel ? Xs : Xn;
  const _Float16* wh = sel ? whS : whN;
  const float* bias = sel ? biasS : biasN;
  const int t = threadIdx.x, lane = t & 63, wv = t >> 6;
  const int nbase = blockIdx.x * 64;
  const int m = lane & 15, quad = lane >> 4;
  f32x4 acc[4][4];
#pragma unroll
  for (int i = 0; i < 4; ++i)
#pragma unroll
    for (int nt = 0; nt < 4; ++nt) acc[i][nt] = (f32x4){0.f, 0.f, 0.f, 0.f};
#pragma unroll
  for (int ks = 0; ks < 4; ++ks) {
    half8 b[4];
#pragma unroll
    for (int nt = 0; nt < 4; ++nt)
      b[nt] = *(const half8*)(wh + (((size_t)(ks * 16 + wv * 4 + nt)) * 64 + lane) * 8);
#pragma unroll
    for (int i = 0; i < 4; ++i) {
      const int row = min(nbase + i * 16 + m, NN - 1);
      const float* src = X + (size_t)row * ldx + ks * 32 + quad * 8;
      const float4 f0 = *(const float4*)src;
      const float4 f1 = *(const float4*)(src + 4);
      half8 a;
      a[0] = (_Float16)f0.x; a[1] = (_Float16)f0.y;
      a[2] = (_Float16)f0.z; a[3] = (_Float16)f0.w;
      a[4] = (_Float16)f1.x; a[5] = (_Float16)f1.y;
      a[6] = (_Float16)f1.z; a[7] = (_Float16)f1.w;
#pragma unroll
      for (int nt = 0; nt < 4; ++nt)
        acc[i][nt] = __builtin_amdgcn_mfma_f32_16x16x32_f16(a, b[nt], acc[i][nt],
                                                            0, 0, 0);
    }
  }
#pragma unroll
  for (int i = 0; i < 4; ++i)
#pragma unroll
    for (int nt = 0; nt < 4; ++nt) {
      const int col = wv * 64 + nt * 16 + m;
      const float bv = (col < CH) ? bias[col] : 0.f;
#pragma unroll
      for (int r = 0; r < 4; ++r) {
        const int row = nbase + i * 16 + quad * 4 + r;
        if (row < NN) {
          const float v = acc[i][nt][r] + bv;
          if (col < CH)
            PQi[((size_t)row * 64 + (col >> 1)) * 4 + sel * 2 + (col & 1)] =
                (_Float16)v;
          else {
            const int qc = col - CH;
            Qi[((size_t)row * 64 + (qc >> 1)) * 4 + sel * 2 + (qc & 1)] =
                (_Float16)v;
          }
        }
      }
    }
}

// ---------- fused dual-stream CSR conv: interleaved PQ (1 gather/edge) ----------
__global__ __launch_bounds__(256) void k_conv2(
    const int* __restrict__ row_ptr, const int* __restrict__ ssrc,
    const _Float16* __restrict__ sea8,
    const _Float16* __restrict__ PQi, const _Float16* __restrict__ Qi,
    const float* __restrict__ Cn, const float* __restrict__ Cs,
    float* __restrict__ feats, float* __restrict__ sfeats,
    int cur, int prev) {
  const int t = threadIdx.x;
  const int lane = t & 63;
  const int node = blockIdx.x * 4 + (t >> 6);
  const int c = lane * 2;
  float2 cwn[EA], cws[EA];
#pragma unroll
  for (int j = 0; j < EA; ++j) {
    cwn[j] = *(const float2*)(Cn + j * CH + c);
    cws[j] = *(const float2*)(Cs + j * CH + c);
  }
  int i0 = __builtin_amdgcn_readfirstlane(row_ptr[node]);
  int i1 = __builtin_amdgcn_readfirstlane(row_ptr[node + 1]);
  const uint2 qv = *(const uint2*)(Qi + ((size_t)node * 64 + lane) * 4);
  const h2 qnh = *(const h2*)&qv.x;
  const h2 qsh = *(const h2*)&qv.y;
  const float2 qn = {(float)qnh[0], (float)qnh[1]};
  const float2 qs = {(float)qsh[0], (float)qsh[1]};
  float an0 = 0.f, an1 = 0.f, as0 = 0.f, as1 = 0.f;
  for (int base = i0; base < i1; base += 64) {
    const int cnt = min(64, i1 - base);
    int s_l = 0;
    uint4 ea_l = {0u, 0u, 0u, 0u};
    if (lane < cnt) {
      s_l = ssrc[base + lane];
      ea_l = *(const uint4*)(sea8 + (size_t)(base + lane) * 8);
    }
#define EDGE_BODY(J)                                                       \
    {                                                                      \
      int s = __shfl(s_l, (J), 64);                                        \
      unsigned w0 = __shfl((int)ea_l.x, (J), 64);                          \
      unsigned w1 = __shfl((int)ea_l.y, (J), 64);                          \
      unsigned w2 = __shfl((int)ea_l.z, (J), 64);                          \
      const h2 ha = *(const h2*)&w0;                                       \
      const h2 hb = *(const h2*)&w1;                                       \
      const h2 hc = *(const h2*)&w2;                                       \
      const float e0 = (float)ha[0], e1 = (float)ha[1];                    \
      const float e2 = (float)hb[0], e3 = (float)hb[1];                    \
      const float e4 = (float)hc[0], e5 = (float)hc[1];                    \
      const uint2 pv = *(const uint2*)(PQi + ((size_t)s * 64 + lane) * 4); \
      const h2 pnv = *(const h2*)&pv.x;                                    \
      const h2 psv = *(const h2*)&pv.y;                                    \
      float vn0 = (float)pnv[0] + qn.x, vn1 = (float)pnv[1] + qn.y;        \
      float vs0 = (float)psv[0] + qs.x, vs1 = (float)psv[1] + qs.y;        \
      vn0 += e0 * cwn[0].x; vn1 += e0 * cwn[0].y;                          \
      vs0 += e0 * cws[0].x; vs1 += e0 * cws[0].y;                          \
      vn0 += e1 * cwn[1].x; vn1 += e1 * cwn[1].y;                          \
      vs0 += e1 * cws[1].x; vs1 += e1 * cws[1].y;                          \
      vn0 += e2 * cwn[2].x; vn1 += e2 * cwn[2].y;                          \
      vs0 += e2 * cws[2].x; vs1 += e2 * cws[2].y;                          \
      vn0 += e3 * cwn[3].x; vn1 += e3 * cwn[3].y;                          \
      vs0 += e3 * cws[3].x; vs1 += e3 * cws[3].y;                          \
      vn0 += e4 * cwn[4].x; vn1 += e4 * cwn[4].y;                          \
      vs0 += e4 * cws[4].x; vs1 += e4 * cws[4].y;                          \
      vn0 += e5 * cwn[5].x; vn1 += e5 * cwn[5].y;                          \
      vs0 += e5 * cws[5].x; vs1 += e5 * cws[5].y;                          \
      an0 = fmaxf(an0, vn0); an1 = fmaxf(an1, vn1);                        \
      as0 += fmaxf(vs0, 0.f); as1 += fmaxf(vs1, 0.f);                      \
    }
    int j = 0;
    for (; j + 4 <= cnt; j += 4) {
      EDGE_BODY(j) EDGE_BODY(j + 1) EDGE_BODY(j + 2) EDGE_BODY(j + 3)
    }
    for (; j < cnt; ++j) EDGE_BODY(j)
#undef EDGE_BODY
  }
  const float inv = 1.f / fmaxf((float)(i1 - i0), 1.f);
  as0 *= inv; as1 *= inv;
  const size_t o = (size_t)node * FUS + (size_t)cur * CH + c;
  if (prev >= 0) {
    const size_t op = (size_t)node * FUS + (size_t)prev * CH + c;
    const float2 prn = *(const float2*)(feats + op);
    const float2 prs = *(const float2*)(sfeats + op);
    an0 += prn.x; an1 += prn.y;
    as0 += prs.x; as1 += prs.y;
  }
  float2 on = {an0, an1}, os = {as0, as1};
  *(float2*)(feats + o) = on;
  *(float2*)(sfeats + o) = os;
}

// ---------- pack feats -> f16 A-fragments: [rb][ks][i][lane][8] ----------
__global__ __launch_bounds__(64) void k_cvtApack(const float* __restrict__ feats,
                                                 _Float16* __restrict__ ap) {
  const int rb = blockIdx.x / 12, ks = blockIdx.x % 12;
  const int L = threadIdx.x, m = L & 15, quad = L >> 4;
#pragma unroll
  for (int i = 0; i < 4; ++i) {
    const int row = rb * 64 + i * 16 + m;
    const int rowc = min(row, NN - 1);
    const float* src = feats + (size_t)rowc * FUS + ks * 32 + quad * 8;
    half8 v;
    if (row < NN) {
      const float4 f0 = *(const float4*)src;
      const float4 f1 = *(const float4*)(src + 4);
      v[0] = (_Float16)f0.x; v[1] = (_Float16)f0.y;
      v[2] = (_Float16)f0.z; v[3] = (_Float16)f0.w;
      v[4] = (_Float16)f1.x; v[5] = (_Float16)f1.y;
      v[6] = (_Float16)f1.z; v[7] = (_Float16)f1.w;
    } else {
#pragma unroll
      for (int j = 0; j < 8; ++j) v[j] = (_Float16)0.f;
    }
    *(half8*)(ap + (((size_t)(rb * 12 + ks) * 4 + i) * 64 + L) * 8) = v;
  }
}

// ---------- convert + pack W (KxN f32) into f16 B-fragment order ----------
template <int N, int NT>
__global__ __launch_bounds__(64) void k_cvtB(const float* __restrict__ W,
                                             _Float16* __restrict__ wh) {
  const int c = blockIdx.x / NT;
  const int tile = blockIdx.x % NT;
  const int L = threadIdx.x;
  const int n = tile * 16 + (L & 15);
  const int k0 = c * 32 + (L >> 4) * 8;
  half8 v;
#pragma unroll
  for (int j = 0; j < 8; ++j) v[j] = (_Float16)W[(size_t)(k0 + j) * N + n];
  *(half8*)(wh + (((size_t)(c * NT + tile)) * 64 + L) * 8) = v;
}

// ---------- fusion GEMM + segment max: 4 col-groups per block ----------
// grid (784, 2): 1568 blocks. A slice (48 KB) read <=2x from HBM (77 MB worst),
// L2-hot within a block. Epilogue uses all 256 threads: col = t&127,
// row-half = t>>7; partial run-merge + atomicMax is partition-safe.
__global__ __launch_bounds__(256) void k_pool_mfma(
    const _Float16* __restrict__ aP, const _Float16* __restrict__ wh,
    const int* __restrict__ bbox, const float* __restrict__ bf,
    float* __restrict__ pooled) {
  __shared__ float cl[64 * 132];
  const int t = threadIdx.x, lane = t & 63, wv = t >> 6;
  const int rb = blockIdx.x;
  const int nbase = rb * 64;
  const int m = lane & 15, quad = lane >> 4;
  const _Float16* apb = aP + (size_t)rb * 12 * 2048 + (size_t)lane * 8;
  for (int cgi = 0; cgi < 4; ++cgi) {
    const int cg = blockIdx.y * 4 + cgi;
    f32x4 acc[4][2];
#pragma unroll
    for (int i = 0; i < 4; ++i)
#pragma unroll
      for (int nt = 0; nt < 2; ++nt) acc[i][nt] = (f32x4){0.f, 0.f, 0.f, 0.f};
    const _Float16* bp = wh + ((size_t)(cg * 8 + wv * 2) * 64 + lane) * 8;
#pragma unroll
    for (int ks = 0; ks < 12; ++ks) {
      const half8 b0 = *(const half8*)(bp + (size_t)ks * 32768);
      const half8 b1 = *(const half8*)(bp + (size_t)ks * 32768 + 512);
#pragma unroll
      for (int i = 0; i < 4; ++i) {
        const half8 a = *(const half8*)(apb + ((size_t)ks * 4 + i) * 512);
        acc[i][0] = __builtin_amdgcn_mfma_f32_16x16x32_f16(a, b0, acc[i][0], 0, 0, 0);
        acc[i][1] = __builtin_amdgcn_mfma_f32_16x16x32_f16(a, b1, acc[i][1], 0, 0, 0);
      }
    }
    __syncthreads();   // previous cg's readers done with cl
#pragma unroll
    for (int i = 0; i < 4; ++i)
#pragma unroll
      for (int nt = 0; nt < 2; ++nt) {
        const int col = wv * 32 + nt * 16 + m;
#pragma unroll
        for (int r = 0; r < 4; ++r)
          cl[(i * 16 + quad * 4 + r) * 132 + col] = acc[i][nt][r];
      }
    __syncthreads();
    {
      const int col = t & 127, rh = t >> 7;
      const int gcol = cg * 128 + col;
      const float bias = bf[gcol];
      int curb = -1;
      float mx = 0.f;
      for (int rr = 0; rr < 32; ++rr) {
        const int row = rh * 32 + rr;
        const int node = nbase + row;
        if (node >= NN) break;
        const int bid = bbox[node];
        const float v = fmaxf(cl[row * 132 + col] + bias, 0.f);
        if (bid != curb) {
          if (curb >= 0)
            atomicMax((unsigned*)(pooled + (size_t)curb * 1408 + gcol),
                      __float_as_uint(mx));
          curb = bid;
          mx = v;
        } else {
          mx = fmaxf(mx, v);
        }
      }
      if (curb >= 0)
        atomicMax((unsigned*)(pooled + (size_t)curb * 1408 + gcol),
                  __float_as_uint(mx));
    }
  }
}

// ---------- raw-feats bbox max + sfeats bbox mean ----------
__global__ __launch_bounds__(256) void k_poolraw(
    const float* __restrict__ feats, const float* __restrict__ sfeats,
    const int* __restrict__ seg, float* __restrict__ pooled,
    float* __restrict__ sb) {
  const int b = blockIdx.x, t = threadIdx.x;
  if (t >= 192) return;
  const int c2 = t * 2;
  const int n0 = __builtin_amdgcn_readfirstlane(seg[b]);
  const int n1 = __builtin_amdgcn_readfirstlane(seg[b + 1]);
  float2 fmx = {0.f, 0.f}, ss = {0.f, 0.f};
  for (int n = n0; n < n1; ++n) {
    const float2 f2 = *(const float2*)(feats + (size_t)n * FUS + c2);
    fmx.x = fmaxf(fmx.x, f2.x); fmx.y = fmaxf(fmx.y, f2.y);
    const float2 s2 = *(const float2*)(sfeats + (size_t)n * FUS + c2);
    ss.x += s2.x; ss.y += s2.y;
  }
  *(float2*)(pooled + (size_t)b * 1408 + 1024 + c2) = fmx;
  const float inv = 1.f / fmaxf((float)(n1 - n0), 1.f);
  float2 o = {ss.x * inv, ss.y * inv};
  *(float2*)(sb + (size_t)b * FUS + c2) = o;
}

// ---------- fusion_super = relu(sb @ Wfs + bfs), lane-distributed x ----------
__global__ __launch_bounds__(256) void k_fusion_super(
    const float* __restrict__ sb, const float* __restrict__ Wfs,
    const float* __restrict__ bfs, float* __restrict__ fs) {
  const int t = threadIdx.x, lane = t & 63, wv = t >> 6;
  const int r0 = blockIdx.x * 4;
  const int c = (blockIdx.y * 4 + wv) * 128 + lane * 2;
  float2 acc[4];
#pragma unroll
  for (int u = 0; u < 4; ++u) acc[u] = make_float2(0.f, 0.f);
  const int xr = r0 + (lane >> 4), xk = lane & 15;
  for (int k0 = 0; k0 < FUS; k0 += 16) {
    const float xv = sb[(size_t)xr * FUS + k0 + xk];
#pragma unroll
    for (int j = 0; j < 16; ++j) {
      const float2 w = *(const float2*)(Wfs + (size_t)(k0 + j) * 1024 + c);
#pragma unroll
      for (int u = 0; u < 4; ++u) {
        const float xs = __shfl(xv, u * 16 + j, 64);
        acc[u].x += xs * w.x; acc[u].y += xs * w.y;
      }
    }
  }
  const float2 b = *(const float2*)(bfs + c);
#pragma unroll
  for (int u = 0; u < 4; ++u) {
    float2 o = {fmaxf(acc[u].x + b.x, 0.f), fmaxf(acc[u].y + b.y, 0.f)};
    *(float2*)(fs + (size_t)(r0 + u) * 1024 + c) = o;
  }
}

// ---------- concat [pooled | fsup | sb] -> f16 bbH[NB_PAD][K1], zero-padded ----
__global__ __launch_bounds__(256) void k_cvt_cat(
    const float* __restrict__ pooled, const float* __restrict__ fsup,
    const float* __restrict__ sb, _Float16* __restrict__ bbH) {
  const size_t off = ((size_t)blockIdx.x * 256 + threadIdx.x) * 8;
  const int row = (int)(off / K1);
  const int col = (int)(off - (size_t)row * K1);
  half8 v;
  if (row < NB) {
    const float* src;
    if (col < 1408)      src = pooled + (size_t)row * 1408 + col;
    else if (col < 2432) src = fsup + (size_t)row * 1024 + (col - 1408);
    else                 src = sb + (size_t)row * FUS + (col - 2432);
    const float4 f0 = *(const float4*)src;
    const float4 f1 = *(const float4*)(src + 4);
    v[0] = (_Float16)f0.x; v[1] = (_Float16)f0.y;
    v[2] = (_Float16)f0.z; v[3] = (_Float16)f0.w;
    v[4] = (_Float16)f1.x; v[5] = (_Float16)f1.y;
    v[6] = (_Float16)f1.z; v[7] = (_Float16)f1.w;
  } else {
#pragma unroll
    for (int j = 0; j < 8; ++j) v[j] = (_Float16)0.f;
  }
  *(half8*)(bbH + off) = v;
}

// ---------- h1 = relu(bbH @ W1 + b1) on matrix cores ----------
__global__ __launch_bounds__(256) void k_mlp1_mfma(
    const _Float16* __restrict__ bbH, const _Float16* __restrict__ wh,
    const float* __restrict__ b1, float* __restrict__ h1) {
  const int t = threadIdx.x, lane = t & 63, wv = t >> 6;
  const int nbase = blockIdx.x * 64;
  const int cg = blockIdx.y;
  const int m = lane & 15, quad = lane >> 4;
  f32x4 acc[4][2];
#pragma unroll
  for (int i = 0; i < 4; ++i)
#pragma unroll
    for (int nt = 0; nt < 2; ++nt) acc[i][nt] = (f32x4){0.f, 0.f, 0.f, 0.f};
  const _Float16* ap = bbH + (size_t)(nbase + m) * K1 + quad * 8;
  const _Float16* bp = wh + ((size_t)(cg * 8 + wv * 2) * 64 + lane) * 8;
#pragma unroll 4
  for (int ks = 0; ks < 88; ++ks) {
    const half8 b0 = *(const half8*)(bp + (size_t)ks * 16384);
    const half8 b1v = *(const half8*)(bp + (size_t)ks * 16384 + 512);
#pragma unroll
    for (int i = 0; i < 4; ++i) {
      const half8 a = *(const half8*)(ap + (size_t)(i * 16) * K1 + ks * 32);
      acc[i][0] = __builtin_amdgcn_mfma_f32_16x16x32_f16(a, b0, acc[i][0], 0, 0, 0);
      acc[i][1] = __builtin_amdgcn_mfma_f32_16x16x32_f16(a, b1v, acc[i][1], 0, 0, 0);
    }
  }
#pragma unroll
  for (int i = 0; i < 4; ++i)
#pragma unroll
    for (int nt = 0; nt < 2; ++nt) {
      const int gcol = cg * 128 + wv * 32 + nt * 16 + m;
      const float bias = b1[gcol];
#pragma unroll
      for (int r = 0; r < 4; ++r) {
        const int row = nbase + i * 16 + quad * 4 + r;
        if (row < NB)
          h1[(size_t)row * 512 + gcol] = fmaxf(acc[i][nt][r] + bias, 0.f);
      }
    }
}

// ---------- h2 = relu(h1 @ W2 + b2) ----------
__global__ __launch_bounds__(256) void k_mlp2(
    const float* __restrict__ h1, const float* __restrict__ W2,
    const float* __restrict__ b2, float* __restrict__ h2o) {
  const int r0 = blockIdx.x * 8, t = threadIdx.x;
  float acc[8];
#pragma unroll
  for (int u = 0; u < 8; ++u) acc[u] = 0.f;
  for (int k = 0; k < 512; ++k) {
    float w = W2[(size_t)k * 256 + t];
#pragma unroll
    for (int u = 0; u < 8; ++u) acc[u] += h1[(size_t)(r0 + u) * 512 + k] * w;
  }
  float bv = b2[t];
#pragma unroll
  for (int u = 0; u < 8; ++u)
    h2o[(size_t)(r0 + u) * 256 + t] = fmaxf(acc[u] + bv, 0.f);
}

// ---------- logits = h2 @ W3 + b3 ----------
__global__ __launch_bounds__(256) void k_mlp3(
    const float* __restrict__ h2i, const float* __restrict__ W3,
    const float* __restrict__ b3, float* __restrict__ out) {
  const int r0 = blockIdx.x * 8, t = threadIdx.x;
  const int u = t >> 5, oc = t & 31;
  const float* x = h2i + (size_t)(r0 + u) * 256;
  float acc = 0.f;
  for (int k = 0; k < 256; ++k) acc += x[k] * W3[(size_t)k * 32 + oc];
  out[(size_t)(r0 + u) * 32 + oc] = acc + b3[oc];
}

extern "C" void kernel_launch(void* const* d_in, const int* in_sizes, int n_in,
                              void* d_out, int out_size, void* d_ws, size_t ws_size,
                              hipStream_t stream) {
  const float* x     = (const float*)d_in[0];
  const float* eattr = (const float*)d_in[1];
  const float* W_h   = (const float*)d_in[2];
  const float* b_h   = (const float*)d_in[3];
  const float* Ws_h  = (const float*)d_in[4];
  const float* bs_h  = (const float*)d_in[5];
  const float* Wb    = (const float*)d_in[6];
  const float* bb    = (const float*)d_in[7];
  const float* Wbs   = (const float*)d_in[8];
  const float* bbs   = (const float*)d_in[9];
  const float* W_f   = (const float*)d_in[10];
  const float* b_f   = (const float*)d_in[11];
  const float* W_fs  = (const float*)d_in[12];
  const float* b_fs  = (const float*)d_in[13];
  const float* W1    = (const float*)d_in[14];
  const float* b1    = (const float*)d_in[15];
  const float* W2    = (const float*)d_in[16];
  const float* b2    = (const float*)d_in[17];
  const float* W3    = (const float*)d_in[18];
  const float* b3    = (const float*)d_in[19];
  const int*   edge  = (const int*)d_in[20];
  const int*   bbox  = (const int*)d_in[21];
  float* out = (float*)d_out;

  // ---- workspace layout (~221.5 MB; known-good budget >= 233 MB) ----
  float* p = (float*)d_ws;
  float* feats  = p; p += (size_t)NN * FUS;
  float* sfeats = p; p += (size_t)NN * FUS;
  float* PQ     = p; p += (size_t)2 * NN * CH;    // 12.8M floats
  _Float16* PQi = (_Float16*)PQ;
  _Float16* Qi  = PQi + (size_t)NN * 256;
  // overlays inside PQ (live only AFTER the last k_conv2):
  _Float16* aPack = (_Float16*)PQ;
  _Float16* WfH   = aPack + (size_t)784 * 12 * 2048;
  float* pooled   = (float*)(WfH + (size_t)FUS * 1024);
  float* sb   = PQ;
  float* fsup = sb + (size_t)NB * FUS;
  float* h1   = fsup + (size_t)NB * 1024;
  float* h2b  = h1 + (size_t)NB * 512;
  _Float16* bbH = (_Float16*)(h2b + (size_t)NB * 256);
  _Float16* W1H = bbH + (size_t)NB_PAD * K1;
  // CSR payload + misc after PQ region:
  _Float16* sea8 = (_Float16*)p;
  int* ssrc    = (int*)(sea8 + (size_t)NE * 8);
  int* row_ptr = ssrc + NE;
  int* deg     = row_ptr + NN + 1;
  int* cursor  = deg + NN;
  int* seg     = cursor + NN;
  _Float16* WcatN = (_Float16*)(seg + NB + 1);
  _Float16* WcatS = WcatN + (size_t)128 * 256;

  hipMemsetAsync(deg, 0, 2 * NN * sizeof(int), stream);  // deg + cursor

  // ---- CSR build (dst-sorted payload) + bbox segments ----
  k_deg<<<(NE + 255) / 256, 256, 0, stream>>>(edge, deg);
  k_scan<<<1, 1024, 0, stream>>>(deg, row_ptr);
  k_fill<<<(NE + 255) / 256, 256, 0, stream>>>(edge, eattr, row_ptr, cursor,
                                               ssrc, sea8);
  k_segstart<<<(NN + 255) / 256, 256, 0, stream>>>(bbox, seg);

  const int npq_grid = (NN + 31) / 32;

  // ---- conv 0 (head): both streams read x (K=8), scalar node transform ----
  k_node_pq<<<npq_grid, 256, 0, stream>>>(x, INCH, INCH, W_h, b_h, PQi, Qi, 0);
  k_node_pq<<<npq_grid, 256, 0, stream>>>(x, INCH, INCH, Ws_h, bs_h, PQi, Qi, 1);
  k_conv2<<<NN / 4, 256, 0, stream>>>(row_ptr, ssrc, sea8, PQi, Qi,
                                      W_h + 2 * INCH * CH, Ws_h + 2 * INCH * CH,
                                      feats, sfeats, 0, -1);

  // ---- residual blocks (K=128): MFMA node transform, both streams ----
  for (int i = 0; i < 2; ++i) {
    const float* Wi  = Wb  + (size_t)i * 262 * CH;
    const float* bi  = bb  + (size_t)i * CH;
    const float* Wsi = Wbs + (size_t)i * 262 * CH;
    const float* bsi = bbs + (size_t)i * CH;
    k_cvtWnpq<<<dim3(64, 2), 64, 0, stream>>>(Wi, Wsi, WcatN, WcatS);
    k_npq_mfma<<<dim3((NN + 63) / 64, 2), 256, 0, stream>>>(
        feats + i * CH, sfeats + i * CH, FUS, WcatN, WcatS, bi, bsi, PQi, Qi);
    k_conv2<<<NN / 4, 256, 0, stream>>>(row_ptr, ssrc, sea8, PQi, Qi,
                                        Wi + 2 * CH * CH, Wsi + 2 * CH * CH,
                                        feats, sfeats, i + 1, i);
  }

  // ---- pooling: packed-A f16 convert + MFMA GEMM + atomicMax ----
  k_cvtApack<<<784 * 12, 64, 0, stream>>>(feats, aPack);
  k_cvtB<1024, 64><<<12 * 64, 64, 0, stream>>>(W_f, WfH);
  hipMemsetAsync(pooled, 0, (size_t)NB * 1408 * sizeof(float), stream);
  k_pool_mfma<<<dim3(784, 2), 256, 0, stream>>>(aPack, WfH, bbox, b_f, pooled);
  k_poolraw<<<NB, 256, 0, stream>>>(feats, sfeats, seg, pooled, sb);
  k_fusion_super<<<dim3(NB / 4, 2), 256, 0, stream>>>(sb, W_fs, b_fs, fsup);

  // ---- head MLP: concat->f16, W1->f16 frag, MFMA GEMM, then small MLPs ----
  k_cvt_cat<<<(int)(((size_t)NB_PAD * K1 / 8) / 256), 256, 0, stream>>>(
      pooled, fsup, sb, bbH);
  k_cvtB<512, 32><<<88 * 32, 64, 0, stream>>>(W1, W1H);
  k_mlp1_mfma<<<dim3(NB_PAD / 64, 4), 256, 0, stream>>>(bbH, W1H, b1, h1);
  k_mlp2<<<NB / 8, 256, 0, stream>>>(h1, W2, b2, h2b);
  k_mlp3<<<NB / 8, 256, 0, stream>>>(h2b, W3, b3, out);
}

// Round 20
// 1080.276 us; speedup vs baseline: 1.0629x; 1.0629x over previous
//
#include <hip/hip_runtime.h>

#define NN      50000
#define NE      800000
#define INCH    8
#define CH      128
#define EA      6
#define NB      2000
#define NB_PAD  2048
#define NCLS    32
#define FUS     384
#define K1      2816   // 1408 + 1024 + 384

typedef _Float16 half8 __attribute__((ext_vector_type(8)));
typedef _Float16 h2 __attribute__((ext_vector_type(2)));
typedef float f32x4 __attribute__((ext_vector_type(4)));

// ---------- degree of dst nodes ----------
__global__ __launch_bounds__(256) void k_deg(const int* __restrict__ edge,
                                             int* __restrict__ deg) {
  int e = blockIdx.x * 256 + threadIdx.x;
  if (e < NE) atomicAdd(&deg[edge[NE + e]], 1);
}

// ---------- exclusive scan of deg -> row_ptr (single block, shfl scan) ----------
__global__ __launch_bounds__(1024) void k_scan(const int* __restrict__ deg,
                                               int* __restrict__ row_ptr) {
  __shared__ int wsum[16];
  __shared__ int s_carry;
  const int t = threadIdx.x, lane = t & 63, w = t >> 6;
  if (t == 0) s_carry = 0;
  __syncthreads();
  for (int base = 0; base < NN; base += 1024) {
    int i = base + t;
    int x = (i < NN) ? deg[i] : 0;
#pragma unroll
    for (int off = 1; off < 64; off <<= 1) {
      int y = __shfl_up(x, off, 64);
      if (lane >= off) x += y;
    }
    if (lane == 63) wsum[w] = x;
    __syncthreads();
    if (w == 0 && lane < 16) {
      int s = wsum[lane];
#pragma unroll
      for (int off = 1; off < 16; off <<= 1) {
        int y = __shfl_up(s, off, 64);
        if (lane >= off) s += y;
      }
      wsum[lane] = s;
    }
    __syncthreads();
    int incl = x + ((w == 0) ? 0 : wsum[w - 1]) + s_carry;
    if (i < NN) row_ptr[i + 1] = incl;
    __syncthreads();
    if (t == 1023) s_carry = incl;
    __syncthreads();
  }
  if (t == 0) row_ptr[0] = 0;
}

// ---------- fill CSR payload: dst-sorted src + f16 e_attr ----------
__global__ __launch_bounds__(256) void k_fill(
    const int* __restrict__ edge, const float* __restrict__ eattr,
    const int* __restrict__ row_ptr, int* __restrict__ cursor,
    int* __restrict__ ssrc, _Float16* __restrict__ sea8) {
  int e = blockIdx.x * 256 + threadIdx.x;
  if (e >= NE) return;
  int s = edge[e], d = edge[NE + e];
  int idx = row_ptr[d] + atomicAdd(&cursor[d], 1);
  ssrc[idx] = s;
  half8 v;
#pragma unroll
  for (int j = 0; j < EA; ++j) v[j] = (_Float16)eattr[(size_t)e * EA + j];
  v[6] = (_Float16)0.f; v[7] = (_Float16)0.f;
  *(half8*)(sea8 + (size_t)idx * 8) = v;
}

// ---------- segment starts from sorted bbox_idx ----------
__global__ __launch_bounds__(256) void k_segstart(const int* __restrict__ bbox,
                                                  int* __restrict__ seg) {
  int i = blockIdx.x * 256 + threadIdx.x;
  if (i >= NN) return;
  int bc = bbox[i];
  int bp = (i == 0) ? -1 : bbox[i - 1];
  for (int j = bp + 1; j <= bc; ++j) seg[j] = i;
  if (i == NN - 1)
    for (int j = bc + 1; j <= NB; ++j) seg[j] = NN;
}

// ---------- head node transform (K=8): scalar path -> interleaved f16 ----------
__global__ __launch_bounds__(256) void k_node_pq(
    const float* __restrict__ X, int ldx, int K,
    const float* __restrict__ W, const float* __restrict__ bias,
    _Float16* __restrict__ PQi, _Float16* __restrict__ Qi, int sel) {
  const int t = threadIdx.x, lane = t & 63, wv = t >> 6;
  const int nbase = blockIdx.x * 32 + wv * 8;
  const int c = lane * 2;
  const float2 bv = *(const float2*)(bias + c);
  float2 pacc[8], qacc[8];
#pragma unroll
  for (int u = 0; u < 8; ++u) { pacc[u] = bv; qacc[u] = make_float2(0.f, 0.f); }
  const int xrow = min(nbase + (lane >> 3), NN - 1);
  const int xk = lane & 7;
  for (int k0 = 0; k0 < K; k0 += 8) {
    const float xv = X[(size_t)xrow * ldx + k0 + xk];
#pragma unroll
    for (int j = 0; j < 8; ++j) {
      const float2 w1 = *(const float2*)(W + (size_t)(k0 + j) * CH + c);
      const float2 w2 = *(const float2*)(W + (size_t)(K + k0 + j) * CH + c);
      const float2 wd = {w1.x - w2.x, w1.y - w2.y};
#pragma unroll
      for (int u = 0; u < 8; ++u) {
        const float xs = __shfl(xv, u * 8 + j, 64);
        pacc[u].x += xs * wd.x; pacc[u].y += xs * wd.y;
        qacc[u].x += xs * w2.x; qacc[u].y += xs * w2.y;
      }
    }
  }
#pragma unroll
  for (int u = 0; u < 8; ++u) {
    const int node = nbase + u;
    if (node < NN) {
      const size_t o = ((size_t)node * 64 + lane) * 4 + sel * 2;
      *(h2*)(PQi + o) = (h2){(_Float16)pacc[u].x, (_Float16)pacc[u].y};
      *(h2*)(Qi + o)  = (h2){(_Float16)qacc[u].x, (_Float16)qacc[u].y};
    }
  }
}

// ---------- pack [W1-W2 | W2] (K=128 x N=256) into f16 B-fragments ----------
__global__ __launch_bounds__(64) void k_cvtWnpq(
    const float* __restrict__ WN, const float* __restrict__ WS,
    _Float16* __restrict__ whN, _Float16* __restrict__ whS) {
  const float* W = blockIdx.y ? WS : WN;
  _Float16* wh   = blockIdx.y ? whS : whN;
  const int c = blockIdx.x >> 4, tile = blockIdx.x & 15;
  const int L = threadIdx.x;
  const int n = tile * 16 + (L & 15);
  const int k0 = c * 32 + (L >> 4) * 8;
  half8 v;
#pragma unroll
  for (int j = 0; j < 8; ++j) {
    const int k = k0 + j;
    float val;
    if (n < CH) val = W[(size_t)k * CH + n] - W[(size_t)(CH + k) * CH + n];
    else        val = W[(size_t)(CH + k) * CH + (n - CH)];
    v[j] = (_Float16)val;
  }
  *(half8*)(wh + (((size_t)(c * 16 + tile)) * 64 + L) * 8) = v;
}

// ---------- residual node transform on matrix cores (both streams) ----------
__global__ __launch_bounds__(256) void k_npq_mfma(
    const float* __restrict__ Xn, const float* __restrict__ Xs, int ldx,
    const _Float16* __restrict__ whN, const _Float16* __restrict__ whS,
    const float* __restrict__ biasN, const float* __restrict__ biasS,
    _Float16* __restrict__ PQi, _Float16* __restrict__ Qi) {
  const int sel = blockIdx.y;
  const float* X = sel ? Xs : Xn;
  const _Float16* wh = sel ? whS : whN;
  const float* bias = sel ? biasS : biasN;
  const int t = threadIdx.x, lane = t & 63, wv = t >> 6;
  const int nbase = blockIdx.x * 64;
  const int m = lane & 15, quad = lane >> 4;
  f32x4 acc[4][4];
#pragma unroll
  for (int i = 0; i < 4; ++i)
#pragma unroll
    for (int nt = 0; nt < 4; ++nt) acc[i][nt] = (f32x4){0.f, 0.f, 0.f, 0.f};
#pragma unroll
  for (int ks = 0; ks < 4; ++ks) {
    half8 b[4];
#pragma unroll
    for (int nt = 0; nt < 4; ++nt)
      b[nt] = *(const half8*)(wh + (((size_t)(ks * 16 + wv * 4 + nt)) * 64 + lane) * 8);
#pragma unroll
    for (int i = 0; i < 4; ++i) {
      const int row = min(nbase + i * 16 + m, NN - 1);
      const float* src = X + (size_t)row * ldx + ks * 32 + quad * 8;
      const float4 f0 = *(const float4*)src;
      const float4 f1 = *(const float4*)(src + 4);
      half8 a;
      a[0] = (_Float16)f0.x; a[1] = (_Float16)f0.y;
      a[2] = (_Float16)f0.z; a[3] = (_Float16)f0.w;
      a[4] = (_Float16)f1.x; a[5] = (_Float16)f1.y;
      a[6] = (_Float16)f1.z; a[7] = (_Float16)f1.w;
#pragma unroll
      for (int nt = 0; nt < 4; ++nt)
        acc[i][nt] = __builtin_amdgcn_mfma_f32_16x16x32_f16(a, b[nt], acc[i][nt],
                                                            0, 0, 0);
    }
  }
#pragma unroll
  for (int i = 0; i < 4; ++i)
#pragma unroll
    for (int nt = 0; nt < 4; ++nt) {
      const int col = wv * 64 + nt * 16 + m;
      const float bv = (col < CH) ? bias[col] : 0.f;
#pragma unroll
      for (int r = 0; r < 4; ++r) {
        const int row = nbase + i * 16 + quad * 4 + r;
        if (row < NN) {
          const float v = acc[i][nt][r] + bv;
          if (col < CH)
            PQi[((size_t)row * 64 + (col >> 1)) * 4 + sel * 2 + (col & 1)] =
                (_Float16)v;
          else {
            const int qc = col - CH;
            Qi[((size_t)row * 64 + (qc >> 1)) * 4 + sel * 2 + (qc & 1)] =
                (_Float16)v;
          }
        }
      }
    }
}

// ---------- fused dual-stream CSR conv: interleaved PQ (1 gather/edge) ----------
__global__ __launch_bounds__(256) void k_conv2(
    const int* __restrict__ row_ptr, const int* __restrict__ ssrc,
    const _Float16* __restrict__ sea8,
    const _Float16* __restrict__ PQi, const _Float16* __restrict__ Qi,
    const float* __restrict__ Cn, const float* __restrict__ Cs,
    float* __restrict__ feats, float* __restrict__ sfeats,
    int cur, int prev) {
  const int t = threadIdx.x;
  const int lane = t & 63;
  const int node = blockIdx.x * 4 + (t >> 6);
  const int c = lane * 2;
  float2 cwn[EA], cws[EA];
#pragma unroll
  for (int j = 0; j < EA; ++j) {
    cwn[j] = *(const float2*)(Cn + j * CH + c);
    cws[j] = *(const float2*)(Cs + j * CH + c);
  }
  int i0 = __builtin_amdgcn_readfirstlane(row_ptr[node]);
  int i1 = __builtin_amdgcn_readfirstlane(row_ptr[node + 1]);
  const uint2 qv = *(const uint2*)(Qi + ((size_t)node * 64 + lane) * 4);
  const h2 qnh = *(const h2*)&qv.x;
  const h2 qsh = *(const h2*)&qv.y;
  const float2 qn = {(float)qnh[0], (float)qnh[1]};
  const float2 qs = {(float)qsh[0], (float)qsh[1]};
  float an0 = 0.f, an1 = 0.f, as0 = 0.f, as1 = 0.f;
  for (int base = i0; base < i1; base += 64) {
    const int cnt = min(64, i1 - base);
    int s_l = 0;
    uint4 ea_l = {0u, 0u, 0u, 0u};
    if (lane < cnt) {
      s_l = ssrc[base + lane];
      ea_l = *(const uint4*)(sea8 + (size_t)(base + lane) * 8);
    }
#define EDGE_BODY(J)                                                       \
    {                                                                      \
      int s = __shfl(s_l, (J), 64);                                        \
      unsigned w0 = __shfl((int)ea_l.x, (J), 64);                          \
      unsigned w1 = __shfl((int)ea_l.y, (J), 64);                          \
      unsigned w2 = __shfl((int)ea_l.z, (J), 64);                          \
      const h2 ha = *(const h2*)&w0;                                       \
      const h2 hb = *(const h2*)&w1;                                       \
      const h2 hc = *(const h2*)&w2;                                       \
      const float e0 = (float)ha[0], e1 = (float)ha[1];                    \
      const float e2 = (float)hb[0], e3 = (float)hb[1];                    \
      const float e4 = (float)hc[0], e5 = (float)hc[1];                    \
      const uint2 pv = *(const uint2*)(PQi + ((size_t)s * 64 + lane) * 4); \
      const h2 pnv = *(const h2*)&pv.x;                                    \
      const h2 psv = *(const h2*)&pv.y;                                    \
      float vn0 = (float)pnv[0] + qn.x, vn1 = (float)pnv[1] + qn.y;        \
      float vs0 = (float)psv[0] + qs.x, vs1 = (float)psv[1] + qs.y;        \
      vn0 += e0 * cwn[0].x; vn1 += e0 * cwn[0].y;                          \
      vs0 += e0 * cws[0].x; vs1 += e0 * cws[0].y;                          \
      vn0 += e1 * cwn[1].x; vn1 += e1 * cwn[1].y;                          \
      vs0 += e1 * cws[1].x; vs1 += e1 * cws[1].y;                          \
      vn0 += e2 * cwn[2].x; vn1 += e2 * cwn[2].y;                          \
      vs0 += e2 * cws[2].x; vs1 += e2 * cws[2].y;                          \
      vn0 += e3 * cwn[3].x; vn1 += e3 * cwn[3].y;                          \
      vs0 += e3 * cws[3].x; vs1 += e3 * cws[3].y;                          \
      vn0 += e4 * cwn[4].x; vn1 += e4 * cwn[4].y;                          \
      vs0 += e4 * cws[4].x; vs1 += e4 * cws[4].y;                          \
      vn0 += e5 * cwn[5].x; vn1 += e5 * cwn[5].y;                          \
      vs0 += e5 * cws[5].x; vs1 += e5 * cws[5].y;                          \
      an0 = fmaxf(an0, vn0); an1 = fmaxf(an1, vn1);                        \
      as0 += fmaxf(vs0, 0.f); as1 += fmaxf(vs1, 0.f);                      \
    }
    int j = 0;
    for (; j + 4 <= cnt; j += 4) {
      EDGE_BODY(j) EDGE_BODY(j + 1) EDGE_BODY(j + 2) EDGE_BODY(j + 3)
    }
    for (; j < cnt; ++j) EDGE_BODY(j)
#undef EDGE_BODY
  }
  const float inv = 1.f / fmaxf((float)(i1 - i0), 1.f);
  as0 *= inv; as1 *= inv;
  const size_t o = (size_t)node * FUS + (size_t)cur * CH + c;
  if (prev >= 0) {
    const size_t op = (size_t)node * FUS + (size_t)prev * CH + c;
    const float2 prn = *(const float2*)(feats + op);
    const float2 prs = *(const float2*)(sfeats + op);
    an0 += prn.x; an1 += prn.y;
    as0 += prs.x; as1 += prs.y;
  }
  float2 on = {an0, an1}, os = {as0, as1};
  *(float2*)(feats + o) = on;
  *(float2*)(sfeats + o) = os;
}

// ---------- pack feats -> f16 A-fragments: [rb][ks][i][lane][8] ----------
__global__ __launch_bounds__(64) void k_cvtApack(const float* __restrict__ feats,
                                                 _Float16* __restrict__ ap) {
  const int rb = blockIdx.x / 12, ks = blockIdx.x % 12;
  const int L = threadIdx.x, m = L & 15, quad = L >> 4;
#pragma unroll
  for (int i = 0; i < 4; ++i) {
    const int row = rb * 64 + i * 16 + m;
    const int rowc = min(row, NN - 1);
    const float* src = feats + (size_t)rowc * FUS + ks * 32 + quad * 8;
    half8 v;
    if (row < NN) {
      const float4 f0 = *(const float4*)src;
      const float4 f1 = *(const float4*)(src + 4);
      v[0] = (_Float16)f0.x; v[1] = (_Float16)f0.y;
      v[2] = (_Float16)f0.z; v[3] = (_Float16)f0.w;
      v[4] = (_Float16)f1.x; v[5] = (_Float16)f1.y;
      v[6] = (_Float16)f1.z; v[7] = (_Float16)f1.w;
    } else {
#pragma unroll
      for (int j = 0; j < 8; ++j) v[j] = (_Float16)0.f;
    }
    *(half8*)(ap + (((size_t)(rb * 12 + ks) * 4 + i) * 64 + L) * 8) = v;
  }
}

// ---------- convert + pack W (KxN f32) into f16 B-fragment order ----------
template <int N, int NT>
__global__ __launch_bounds__(64) void k_cvtB(const float* __restrict__ W,
                                             _Float16* __restrict__ wh) {
  const int c = blockIdx.x / NT;
  const int tile = blockIdx.x % NT;
  const int L = threadIdx.x;
  const int n = tile * 16 + (L & 15);
  const int k0 = c * 32 + (L >> 4) * 8;
  half8 v;
#pragma unroll
  for (int j = 0; j < 8; ++j) v[j] = (_Float16)W[(size_t)(k0 + j) * N + n];
  *(half8*)(wh + (((size_t)(c * NT + tile)) * 64 + L) * 8) = v;
}

// ---------- fusion GEMM + segment max: R17 config (best measured: 113us) ----
// 1D grid 784*8, XCD swizzle (xcd=fid&7, contiguous 98-rb range per xcd),
// 1 cg per block (max parallelism), packed-A. Epilogue on all 256 threads:
// col = t&127, row-half = t>>7; partial run-merge + atomicMax is safe.
__global__ __launch_bounds__(256) void k_pool_mfma(
    const _Float16* __restrict__ aP, const _Float16* __restrict__ wh,
    const int* __restrict__ bbox, const float* __restrict__ bf,
    float* __restrict__ pooled) {
  __shared__ float cl[64 * 132];
  const int t = threadIdx.x, lane = t & 63, wv = t >> 6;
  const int fid = blockIdx.x;
  const int xcd = fid & 7, slot = fid >> 3;
  const int cg = slot / 98;
  const int rb = xcd * 98 + slot % 98;
  const int nbase = rb * 64;
  const int m = lane & 15, quad = lane >> 4;
  f32x4 acc[4][2];
#pragma unroll
  for (int i = 0; i < 4; ++i)
#pragma unroll
    for (int nt = 0; nt < 2; ++nt) acc[i][nt] = (f32x4){0.f, 0.f, 0.f, 0.f};
  const _Float16* apb = aP + (size_t)rb * 12 * 2048 + (size_t)lane * 8;
  const _Float16* bp = wh + ((size_t)(cg * 8 + wv * 2) * 64 + lane) * 8;
#pragma unroll
  for (int ks = 0; ks < 12; ++ks) {
    const half8 b0 = *(const half8*)(bp + (size_t)ks * 32768);
    const half8 b1 = *(const half8*)(bp + (size_t)ks * 32768 + 512);
#pragma unroll
    for (int i = 0; i < 4; ++i) {
      const half8 a = *(const half8*)(apb + ((size_t)ks * 4 + i) * 512);
      acc[i][0] = __builtin_amdgcn_mfma_f32_16x16x32_f16(a, b0, acc[i][0], 0, 0, 0);
      acc[i][1] = __builtin_amdgcn_mfma_f32_16x16x32_f16(a, b1, acc[i][1], 0, 0, 0);
    }
  }
#pragma unroll
  for (int i = 0; i < 4; ++i)
#pragma unroll
    for (int nt = 0; nt < 2; ++nt) {
      const int col = wv * 32 + nt * 16 + m;
#pragma unroll
      for (int r = 0; r < 4; ++r)
        cl[(i * 16 + quad * 4 + r) * 132 + col] = acc[i][nt][r];
    }
  __syncthreads();
  {
    const int col = t & 127, rh = t >> 7;
    const int gcol = cg * 128 + col;
    const float bias = bf[gcol];
    int curb = -1;
    float mx = 0.f;
    for (int rr = 0; rr < 32; ++rr) {
      const int row = rh * 32 + rr;
      const int node = nbase + row;
      if (node >= NN) break;
      const int bid = bbox[node];
      const float v = fmaxf(cl[row * 132 + col] + bias, 0.f);
      if (bid != curb) {
        if (curb >= 0)
          atomicMax((unsigned*)(pooled + (size_t)curb * 1408 + gcol),
                    __float_as_uint(mx));
        curb = bid;
        mx = v;
      } else {
        mx = fmaxf(mx, v);
      }
    }
    if (curb >= 0)
      atomicMax((unsigned*)(pooled + (size_t)curb * 1408 + gcol),
                __float_as_uint(mx));
  }
}

// ---------- raw-feats bbox max + sfeats bbox mean ----------
__global__ __launch_bounds__(256) void k_poolraw(
    const float* __restrict__ feats, const float* __restrict__ sfeats,
    const int* __restrict__ seg, float* __restrict__ pooled,
    float* __restrict__ sb) {
  const int b = blockIdx.x, t = threadIdx.x;
  if (t >= 192) return;
  const int c2 = t * 2;
  const int n0 = __builtin_amdgcn_readfirstlane(seg[b]);
  const int n1 = __builtin_amdgcn_readfirstlane(seg[b + 1]);
  float2 fmx = {0.f, 0.f}, ss = {0.f, 0.f};
  for (int n = n0; n < n1; ++n) {
    const float2 f2 = *(const float2*)(feats + (size_t)n * FUS + c2);
    fmx.x = fmaxf(fmx.x, f2.x); fmx.y = fmaxf(fmx.y, f2.y);
    const float2 s2 = *(const float2*)(sfeats + (size_t)n * FUS + c2);
    ss.x += s2.x; ss.y += s2.y;
  }
  *(float2*)(pooled + (size_t)b * 1408 + 1024 + c2) = fmx;
  const float inv = 1.f / fmaxf((float)(n1 - n0), 1.f);
  float2 o = {ss.x * inv, ss.y * inv};
  *(float2*)(sb + (size_t)b * FUS + c2) = o;
}

// ---------- fusion_super = relu(sb @ Wfs + bfs), lane-distributed x ----------
__global__ __launch_bounds__(256) void k_fusion_super(
    const float* __restrict__ sb, const float* __restrict__ Wfs,
    const float* __restrict__ bfs, float* __restrict__ fs) {
  const int t = threadIdx.x, lane = t & 63, wv = t >> 6;
  const int r0 = blockIdx.x * 4;
  const int c = (blockIdx.y * 4 + wv) * 128 + lane * 2;
  float2 acc[4];
#pragma unroll
  for (int u = 0; u < 4; ++u) acc[u] = make_float2(0.f, 0.f);
  const int xr = r0 + (lane >> 4), xk = lane & 15;
  for (int k0 = 0; k0 < FUS; k0 += 16) {
    const float xv = sb[(size_t)xr * FUS + k0 + xk];
#pragma unroll
    for (int j = 0; j < 16; ++j) {
      const float2 w = *(const float2*)(Wfs + (size_t)(k0 + j) * 1024 + c);
#pragma unroll
      for (int u = 0; u < 4; ++u) {
        const float xs = __shfl(xv, u * 16 + j, 64);
        acc[u].x += xs * w.x; acc[u].y += xs * w.y;
      }
    }
  }
  const float2 b = *(const float2*)(bfs + c);
#pragma unroll
  for (int u = 0; u < 4; ++u) {
    float2 o = {fmaxf(acc[u].x + b.x, 0.f), fmaxf(acc[u].y + b.y, 0.f)};
    *(float2*)(fs + (size_t)(r0 + u) * 1024 + c) = o;
  }
}

// ---------- concat [pooled | fsup | sb] -> f16 bbH[NB_PAD][K1], zero-padded ----
__global__ __launch_bounds__(256) void k_cvt_cat(
    const float* __restrict__ pooled, const float* __restrict__ fsup,
    const float* __restrict__ sb, _Float16* __restrict__ bbH) {
  const size_t off = ((size_t)blockIdx.x * 256 + threadIdx.x) * 8;
  const int row = (int)(off / K1);
  const int col = (int)(off - (size_t)row * K1);
  half8 v;
  if (row < NB) {
    const float* src;
    if (col < 1408)      src = pooled + (size_t)row * 1408 + col;
    else if (col < 2432) src = fsup + (size_t)row * 1024 + (col - 1408);
    else                 src = sb + (size_t)row * FUS + (col - 2432);
    const float4 f0 = *(const float4*)src;
    const float4 f1 = *(const float4*)(src + 4);
    v[0] = (_Float16)f0.x; v[1] = (_Float16)f0.y;
    v[2] = (_Float16)f0.z; v[3] = (_Float16)f0.w;
    v[4] = (_Float16)f1.x; v[5] = (_Float16)f1.y;
    v[6] = (_Float16)f1.z; v[7] = (_Float16)f1.w;
  } else {
#pragma unroll
    for (int j = 0; j < 8; ++j) v[j] = (_Float16)0.f;
  }
  *(half8*)(bbH + off) = v;
}

// ---------- h1 = relu(bbH @ W1 + b1) on matrix cores ----------
__global__ __launch_bounds__(256) void k_mlp1_mfma(
    const _Float16* __restrict__ bbH, const _Float16* __restrict__ wh,
    const float* __restrict__ b1, float* __restrict__ h1) {
  const int t = threadIdx.x, lane = t & 63, wv = t >> 6;
  const int nbase = blockIdx.x * 64;
  const int cg = blockIdx.y;
  const int m = lane & 15, quad = lane >> 4;
  f32x4 acc[4][2];
#pragma unroll
  for (int i = 0; i < 4; ++i)
#pragma unroll
    for (int nt = 0; nt < 2; ++nt) acc[i][nt] = (f32x4){0.f, 0.f, 0.f, 0.f};
  const _Float16* ap = bbH + (size_t)(nbase + m) * K1 + quad * 8;
  const _Float16* bp = wh + ((size_t)(cg * 8 + wv * 2) * 64 + lane) * 8;
#pragma unroll 4
  for (int ks = 0; ks < 88; ++ks) {
    const half8 b0 = *(const half8*)(bp + (size_t)ks * 16384);
    const half8 b1v = *(const half8*)(bp + (size_t)ks * 16384 + 512);
#pragma unroll
    for (int i = 0; i < 4; ++i) {
      const half8 a = *(const half8*)(ap + (size_t)(i * 16) * K1 + ks * 32);
      acc[i][0] = __builtin_amdgcn_mfma_f32_16x16x32_f16(a, b0, acc[i][0], 0, 0, 0);
      acc[i][1] = __builtin_amdgcn_mfma_f32_16x16x32_f16(a, b1v, acc[i][1], 0, 0, 0);
    }
  }
#pragma unroll
  for (int i = 0; i < 4; ++i)
#pragma unroll
    for (int nt = 0; nt < 2; ++nt) {
      const int gcol = cg * 128 + wv * 32 + nt * 16 + m;
      const float bias = b1[gcol];
#pragma unroll
      for (int r = 0; r < 4; ++r) {
        const int row = nbase + i * 16 + quad * 4 + r;
        if (row < NB)
          h1[(size_t)row * 512 + gcol] = fmaxf(acc[i][nt][r] + bias, 0.f);
      }
    }
}

// ---------- h2 = relu(h1 @ W2 + b2) ----------
__global__ __launch_bounds__(256) void k_mlp2(
    const float* __restrict__ h1, const float* __restrict__ W2,
    const float* __restrict__ b2, float* __restrict__ h2o) {
  const int r0 = blockIdx.x * 8, t = threadIdx.x;
  float acc[8];
#pragma unroll
  for (int u = 0; u < 8; ++u) acc[u] = 0.f;
  for (int k = 0; k < 512; ++k) {
    float w = W2[(size_t)k * 256 + t];
#pragma unroll
    for (int u = 0; u < 8; ++u) acc[u] += h1[(size_t)(r0 + u) * 512 + k] * w;
  }
  float bv = b2[t];
#pragma unroll
  for (int u = 0; u < 8; ++u)
    h2o[(size_t)(r0 + u) * 256 + t] = fmaxf(acc[u] + bv, 0.f);
}

// ---------- logits = h2 @ W3 + b3 ----------
__global__ __launch_bounds__(256) void k_mlp3(
    const float* __restrict__ h2i, const float* __restrict__ W3,
    const float* __restrict__ b3, float* __restrict__ out) {
  const int r0 = blockIdx.x * 8, t = threadIdx.x;
  const int u = t >> 5, oc = t & 31;
  const float* x = h2i + (size_t)(r0 + u) * 256;
  float acc = 0.f;
  for (int k = 0; k < 256; ++k) acc += x[k] * W3[(size_t)k * 32 + oc];
  out[(size_t)(r0 + u) * 32 + oc] = acc + b3[oc];
}

extern "C" void kernel_launch(void* const* d_in, const int* in_sizes, int n_in,
                              void* d_out, int out_size, void* d_ws, size_t ws_size,
                              hipStream_t stream) {
  const float* x     = (const float*)d_in[0];
  const float* eattr = (const float*)d_in[1];
  const float* W_h   = (const float*)d_in[2];
  const float* b_h   = (const float*)d_in[3];
  const float* Ws_h  = (const float*)d_in[4];
  const float* bs_h  = (const float*)d_in[5];
  const float* Wb    = (const float*)d_in[6];
  const float* bb    = (const float*)d_in[7];
  const float* Wbs   = (const float*)d_in[8];
  const float* bbs   = (const float*)d_in[9];
  const float* W_f   = (const float*)d_in[10];
  const float* b_f   = (const float*)d_in[11];
  const float* W_fs  = (const float*)d_in[12];
  const float* b_fs  = (const float*)d_in[13];
  const float* W1    = (const float*)d_in[14];
  const float* b1    = (const float*)d_in[15];
  const float* W2    = (const float*)d_in[16];
  const float* b2    = (const float*)d_in[17];
  const float* W3    = (const float*)d_in[18];
  const float* b3    = (const float*)d_in[19];
  const int*   edge  = (const int*)d_in[20];
  const int*   bbox  = (const int*)d_in[21];
  float* out = (float*)d_out;

  // ---- workspace layout (~221.5 MB; known-good budget >= 233 MB) ----
  float* p = (float*)d_ws;
  float* feats  = p; p += (size_t)NN * FUS;
  float* sfeats = p; p += (size_t)NN * FUS;
  float* PQ     = p; p += (size_t)2 * NN * CH;    // 12.8M floats
  _Float16* PQi = (_Float16*)PQ;
  _Float16* Qi  = PQi + (size_t)NN * 256;
  // overlays inside PQ (live only AFTER the last k_conv2):
  _Float16* aPack = (_Float16*)PQ;
  _Float16* WfH   = aPack + (size_t)784 * 12 * 2048;
  float* pooled   = (float*)(WfH + (size_t)FUS * 1024);
  float* sb   = PQ;
  float* fsup = sb + (size_t)NB * FUS;
  float* h1   = fsup + (size_t)NB * 1024;
  float* h2b  = h1 + (size_t)NB * 512;
  _Float16* bbH = (_Float16*)(h2b + (size_t)NB * 256);
  _Float16* W1H = bbH + (size_t)NB_PAD * K1;
  // CSR payload + misc after PQ region:
  _Float16* sea8 = (_Float16*)p;
  int* ssrc    = (int*)(sea8 + (size_t)NE * 8);
  int* row_ptr = ssrc + NE;
  int* deg     = row_ptr + NN + 1;
  int* cursor  = deg + NN;
  int* seg     = cursor + NN;
  _Float16* WcatN = (_Float16*)(seg + NB + 1);
  _Float16* WcatS = WcatN + (size_t)128 * 256;

  hipMemsetAsync(deg, 0, 2 * NN * sizeof(int), stream);  // deg + cursor

  // ---- CSR build (dst-sorted payload) + bbox segments ----
  k_deg<<<(NE + 255) / 256, 256, 0, stream>>>(edge, deg);
  k_scan<<<1, 1024, 0, stream>>>(deg, row_ptr);
  k_fill<<<(NE + 255) / 256, 256, 0, stream>>>(edge, eattr, row_ptr, cursor,
                                               ssrc, sea8);
  k_segstart<<<(NN + 255) / 256, 256, 0, stream>>>(bbox, seg);

  const int npq_grid = (NN + 31) / 32;

  // ---- conv 0 (head): both streams read x (K=8), scalar node transform ----
  k_node_pq<<<npq_grid, 256, 0, stream>>>(x, INCH, INCH, W_h, b_h, PQi, Qi, 0);
  k_node_pq<<<npq_grid, 256, 0, stream>>>(x, INCH, INCH, Ws_h, bs_h, PQi, Qi, 1);
  k_conv2<<<NN / 4, 256, 0, stream>>>(row_ptr, ssrc, sea8, PQi, Qi,
                                      W_h + 2 * INCH * CH, Ws_h + 2 * INCH * CH,
                                      feats, sfeats, 0, -1);

  // ---- residual blocks (K=128): MFMA node transform, both streams ----
  for (int i = 0; i < 2; ++i) {
    const float* Wi  = Wb  + (size_t)i * 262 * CH;
    const float* bi  = bb  + (size_t)i * CH;
    const float* Wsi = Wbs + (size_t)i * 262 * CH;
    const float* bsi = bbs + (size_t)i * CH;
    k_cvtWnpq<<<dim3(64, 2), 64, 0, stream>>>(Wi, Wsi, WcatN, WcatS);
    k_npq_mfma<<<dim3((NN + 63) / 64, 2), 256, 0, stream>>>(
        feats + i * CH, sfeats + i * CH, FUS, WcatN, WcatS, bi, bsi, PQi, Qi);
    k_conv2<<<NN / 4, 256, 0, stream>>>(row_ptr, ssrc, sea8, PQi, Qi,
                                        Wi + 2 * CH * CH, Wsi + 2 * CH * CH,
                                        feats, sfeats, i + 1, i);
  }

  // ---- pooling: packed-A f16 convert + MFMA GEMM (R17 config) + atomicMax ----
  k_cvtApack<<<784 * 12, 64, 0, stream>>>(feats, aPack);
  k_cvtB<1024, 64><<<12 * 64, 64, 0, stream>>>(W_f, WfH);
  hipMemsetAsync(pooled, 0, (size_t)NB * 1408 * sizeof(float), stream);
  k_pool_mfma<<<784 * 8, 256, 0, stream>>>(aPack, WfH, bbox, b_f, pooled);
  k_poolraw<<<NB, 256, 0, stream>>>(feats, sfeats, seg, pooled, sb);
  k_fusion_super<<<dim3(NB / 4, 2), 256, 0, stream>>>(sb, W_fs, b_fs, fsup);

  // ---- head MLP: concat->f16, W1->f16 frag, MFMA GEMM, then small MLPs ----
  k_cvt_cat<<<(int)(((size_t)NB_PAD * K1 / 8) / 256), 256, 0, stream>>>(
      pooled, fsup, sb, bbH);
  k_cvtB<512, 32><<<88 * 32, 64, 0, stream>>>(W1, W1H);
  k_mlp1_mfma<<<dim3(NB_PAD / 64, 4), 256, 0, stream>>>(bbH, W1H, b1, h1);
  k_mlp2<<<NB / 8, 256, 0, stream>>>(h1, W2, b2, h2b);
  k_mlp3<<<NB / 8, 256, 0, stream>>>(h2b, W3, b3, out);
}